// Round 9
// baseline (185.370 us; speedup 1.0000x reference)
//
#include <hip/hip_runtime.h>

// Problem constants (B=1 throughout)
#define SC 6       // cameras
#define NQ 6400    // queries
#define CH 128     // channels
#define HSY 32     // feature H
#define WSX 88     // feature W
#define MV 2816    // HSY*WSX
#define NH 4       // heads
#define NP 20      // points
#define DD 4       // Z anchors (D)
#define DHC 32     // CH/NH
#define NPG 5      // NP/DD

// mega-kernel block roles
#define QB2 16
#define VB2 32
#define NB_QPROJ (NQ / QB2)            // 400
#define NB_VPROJ (SC * MV / VB2)       // 528
#define NB_MEGA  (1 + NB_QPROJ + NB_VPROJ)

// ---------------- workspace layout (float indices) ----------------
#define WS_QOFF     38464
#define WS_AW       1062464
#define WS_VAL      1574464

__device__ __forceinline__ unsigned short f32_to_bf16(float x) {
    unsigned int u = __float_as_uint(x);
    unsigned int r = (u + 0x7FFFu + ((u >> 16) & 1u)) >> 16;   // RNE
    return (unsigned short)r;
}

// ---------------- K1: mega (detect | qproj | vproj), role by blockIdx ----------------
__global__ __launch_bounds__(256) void k_mega(
        const unsigned int* __restrict__ bm,
        const float* __restrict__ q, const float* __restrict__ qpos,
        const float* __restrict__ Woff, const float* __restrict__ boff,
        const float* __restrict__ Wattn, const float* __restrict__ battn,
        const float* __restrict__ value, const float* __restrict__ Wv,
        const float* __restrict__ bv,
        int* __restrict__ flag, float* __restrict__ qoff,
        float* __restrict__ aw, unsigned short* __restrict__ valw) {
    __shared__ __align__(16) float smem[4096 + QB2 * NH * NP];   // 16 KB + lg
    int bid = blockIdx.x;
    int t = threadIdx.x;

    if (bid == 0) {
        // ---- detection: scan first 2048 words (safe under all 3 layouts;
        // 30% bernoulli density -> conclusive with P(fail) ~ 0.7^2048) ----
        unsigned int* r_or = (unsigned int*)smem;
        unsigned int* r_vi = r_or + 256;
        unsigned int o = 0u, v = 0u;
        for (int i = t; i < 2048; i += 256) {
            unsigned int w = bm[i];
            o |= (w & 0xFFFFFF00u);
            v |= (unsigned int)((w != 0u) & (w != 0x3F800000u));
        }
        r_or[t] = o; r_vi[t] = v;
        __syncthreads();
        for (int s = 128; s > 0; s >>= 1) {
            if (t < s) { r_or[t] |= r_or[t + s]; r_vi[t] |= r_vi[t + s]; }
            __syncthreads();
        }
        if (t == 0) {
            int f;
            if (!r_vi[0]) f = 2;          // float32 (or all-zero)
            else if (r_or[0]) f = 1;      // byte-packed bool
            else f = 0;                   // int32
            *flag = f;
        }
        return;
    }

    if (bid <= NB_QPROJ) {
        // ---- query projections + softmax, 16 queries/block ----
        float (*qs)[QB2] = (float(*)[QB2])smem;                     // [128][16]
        float (*lg)[NH * NP] = (float(*)[NH * NP])(smem + 4096);    // [16][80]
        int n0 = (bid - 1) * QB2;
        for (int i = t; i < QB2 * CH; i += 256) {
            int qi = i >> 7, k = i & 127;
            int gi = (n0 + qi) * CH + k;
            qs[k][qi] = q[gi] + qpos[gi];
        }
        __syncthreads();
        if (t < 160) {
            float acc[QB2];
#pragma unroll
            for (int qi = 0; qi < QB2; ++qi) acc[qi] = 0.f;
            for (int k = 0; k < CH; ++k) {
                float w = Woff[k * 160 + t];
#pragma unroll
                for (int v4 = 0; v4 < QB2 / 4; ++v4) {
                    float4 a = *(const float4*)&qs[k][v4 * 4];
                    acc[v4 * 4 + 0] += a.x * w; acc[v4 * 4 + 1] += a.y * w;
                    acc[v4 * 4 + 2] += a.z * w; acc[v4 * 4 + 3] += a.w * w;
                }
            }
            float b = boff[t];
#pragma unroll
            for (int qi = 0; qi < QB2; ++qi) qoff[(n0 + qi) * 160 + t] = acc[qi] + b;
        } else if (t < 240) {
            int j = t - 160;
            float acc[QB2];
#pragma unroll
            for (int qi = 0; qi < QB2; ++qi) acc[qi] = 0.f;
            for (int k = 0; k < CH; ++k) {
                float w = Wattn[k * 80 + j];
#pragma unroll
                for (int v4 = 0; v4 < QB2 / 4; ++v4) {
                    float4 a = *(const float4*)&qs[k][v4 * 4];
                    acc[v4 * 4 + 0] += a.x * w; acc[v4 * 4 + 1] += a.y * w;
                    acc[v4 * 4 + 2] += a.z * w; acc[v4 * 4 + 3] += a.w * w;
                }
            }
            float b = battn[j];
#pragma unroll
            for (int qi = 0; qi < QB2; ++qi) lg[qi][j] = acc[qi] + b;
        }
        __syncthreads();
        if (t < QB2 * NH) {
            int qi = t >> 2, h = t & 3;
            float mx = -1e30f;
#pragma unroll
            for (int p = 0; p < NP; ++p) mx = fmaxf(mx, lg[qi][h * NP + p]);
            float e[NP];
            float sm = 0.f;
#pragma unroll
            for (int p = 0; p < NP; ++p) { e[p] = __expf(lg[qi][h * NP + p] - mx); sm += e[p]; }
            float inv = 1.f / sm;
#pragma unroll
            for (int p = 0; p < NP; ++p) aw[(n0 + qi) * 80 + h * NP + p] = e[p] * inv;
        }
        return;
    }

    // ---- value projection -> bf16 (s,h,m,dh), 32 rows/block ----
    {
        float (*vs)[VB2] = (float(*)[VB2])smem;            // [128][32] = 16 KB
        int r0 = (bid - 1 - NB_QPROJ) * VB2;
        for (int i = t; i < VB2 * CH; i += 256) {
            int ri = i & (VB2 - 1), k = i / VB2;
            vs[k][ri] = value[(size_t)(r0 + ri) * CH + k];
        }
        __syncthreads();
        int c = t & 127, rh = t >> 7;    // rh: row half (0: rows 0-15, 1: rows 16-31)
        float acc[16];
#pragma unroll
        for (int ri = 0; ri < 16; ++ri) acc[ri] = 0.f;
        for (int k = 0; k < CH; ++k) {
            float w = Wv[k * CH + c];
#pragma unroll
            for (int v4 = 0; v4 < 4; ++v4) {
                float4 a = *(const float4*)&vs[k][rh * 16 + v4 * 4];
                acc[v4 * 4 + 0] += a.x * w; acc[v4 * 4 + 1] += a.y * w;
                acc[v4 * 4 + 2] += a.z * w; acc[v4 * 4 + 3] += a.w * w;
            }
        }
        float b = bv[c];
        int h = c >> 5, dh = c & 31;
        int s = r0 / MV;                 // VB2 | MV so block never straddles cameras
        int m0 = r0 - s * MV + rh * 16;
        size_t obase = (size_t)((s * NH + h) * MV) * DHC + dh;
#pragma unroll
        for (int ri = 0; ri < 16; ++ri) {
            valw[obase + (size_t)(m0 + ri) * DHC] = f32_to_bf16(acc[ri] + b);
        }
    }
}

// ---------------- K2: sample (2 queries/block, reg coords) + fused out-proj ----------------
#define REDP 36   // padded red row stride (words)
__global__ __launch_bounds__(320) void k_sample3(
        const float* __restrict__ ref, const float* __restrict__ qoff,
        const float* __restrict__ aw, const void* __restrict__ bm,
        const int* __restrict__ flag, const unsigned short* __restrict__ valw,
        const float* __restrict__ Wout, const float* __restrict__ bout,
        const float* __restrict__ query, float* __restrict__ out) {
    int bid = blockIdx.x;
    int pi = (bid & 7) * (NQ / 16) + (bid >> 3);   // XCD-chunked, bijective (3200%8==0)
    int n0 = pi * 2;                                // queries n0, n0+1
    int t = threadIdx.x;

    __shared__ float qo[2][160];
    __shared__ float awl[2][NH * NP];
    __shared__ float rf[2][SC][DD][2];
    __shared__ float mk[2][SC];
    __shared__ float red[2][80][REDP];    // both queries' partials
    __shared__ float sl[2][CH];

    {
        int qq = t / 160, idx = t - qq * 160;     // 320 threads exactly
        qo[qq][idx] = qoff[(size_t)(n0 + qq) * 160 + idx];
    }
    if (t < 160) {
        int qq = t / 80, idx = t - qq * 80;
        awl[qq][idx] = aw[(size_t)(n0 + qq) * 80 + idx];
    }
    if (t >= 160 && t < 256) {
        int i = t - 160;
        int qq = i / 48, rem = i - qq * 48;
        int s = rem >> 3, r2 = rem & 7;
        rf[qq][s][r2 >> 1][r2 & 1] = ref[(size_t)(s * NQ + n0 + qq) * 8 + r2];
    }
    if (t >= 256 && t < 256 + 2 * SC) {
        int i = t - 256;
        int qq = i / SC, s = i - qq * SC;
        int gi = s * NQ + n0 + qq;
        int f = *flag;
        int any;
        if (f == 1) {
            const unsigned char* p = (const unsigned char*)bm + (size_t)gi * 4;
            any = (int)(p[0] | p[1] | p[2] | p[3]);
        } else if (f == 0) {
            const int* p = (const int*)bm + (size_t)gi * 4;
            any = p[0] | p[1] | p[2] | p[3];
        } else {
            const float* p = (const float*)bm + (size_t)gi * 4;
            any = (p[0] != 0.f) | (p[1] != 0.f) | (p[2] != 0.f) | (p[3] != 0.f);
        }
        mk[qq][s] = any ? 1.0f : 0.0f;
    }
    __syncthreads();

    // ---- gather loop: pair slot sid handles (h,p) for both queries, all cams ----
    int sid = t >> 2;            // 0..79
    int c8 = t & 3;
    int coff = c8 * 8;
    int h = sid & 3, p = sid >> 2;
    int g = p >> 2, d = p & 3;
    int oidx = ((h * NPG + g) * DD + d) * 2;
    float qox0 = qo[0][oidx], qoy0 = qo[0][oidx + 1];
    float qox1 = qo[1][oidx], qoy1 = qo[1][oidx + 1];
    float aw0 = awl[0][h * NP + p], aw1 = awl[1][h * NP + p];

    float acc0[8], acc1[8];
#pragma unroll
    for (int j = 0; j < 8; ++j) { acc0[j] = 0.f; acc1[j] = 0.f; }

#define SAMPLE_Q(ACC, RFX, RFY, QOX, QOY, AWQ, MKQ)  {                         \
        float x = (RFX) * (float)WSX + (QOX) - 0.5f;                           \
        float y = (RFY) * (float)HSY + (QOY) - 0.5f;                           \
        float xf = floorf(x), yf = floorf(y);                                  \
        float wx = x - xf, wy = y - yf;                                        \
        int x0 = (int)xf, y0 = (int)yf;                                        \
        int x1 = x0 + 1, y1 = y0 + 1;                                          \
        float vx0 = (x0 >= 0 && x0 < WSX) ? 1.f : 0.f;                         \
        float vx1 = (x1 >= 0 && x1 < WSX) ? 1.f : 0.f;                         \
        float vy0 = (y0 >= 0 && y0 < HSY) ? 1.f : 0.f;                         \
        float vy1 = (y1 >= 0 && y1 < HSY) ? 1.f : 0.f;                         \
        int cx0 = min(max(x0, 0), WSX - 1), cx1 = min(max(x1, 0), WSX - 1);    \
        int cy0 = min(max(y0, 0), HSY - 1), cy1 = min(max(y1, 0), HSY - 1);    \
        float a_ = (AWQ) * (MKQ);                                              \
        float w00 = (1.f - wx) * (1.f - wy) * vx0 * vy0 * a_;                  \
        float w01 = wx * (1.f - wy) * vx1 * vy0 * a_;                          \
        float w10 = (1.f - wx) * wy * vx0 * vy1 * a_;                          \
        float w11 = wx * wy * vx1 * vy1 * a_;                                  \
        const unsigned short* vb = valw + (size_t)base_s * DHC + coff;         \
        uint4 u00 = *(const uint4*)(vb + (cy0 * WSX + cx0) * DHC);             \
        uint4 u01 = *(const uint4*)(vb + (cy0 * WSX + cx1) * DHC);             \
        uint4 u10 = *(const uint4*)(vb + (cy1 * WSX + cx0) * DHC);             \
        uint4 u11 = *(const uint4*)(vb + (cy1 * WSX + cx1) * DHC);             \
        ACC[0] += w00 * __uint_as_float(u00.x << 16) + w01 * __uint_as_float(u01.x << 16)          \
                + w10 * __uint_as_float(u10.x << 16) + w11 * __uint_as_float(u11.x << 16);         \
        ACC[1] += w00 * __uint_as_float(u00.x & 0xFFFF0000u) + w01 * __uint_as_float(u01.x & 0xFFFF0000u)  \
                + w10 * __uint_as_float(u10.x & 0xFFFF0000u) + w11 * __uint_as_float(u11.x & 0xFFFF0000u); \
        ACC[2] += w00 * __uint_as_float(u00.y << 16) + w01 * __uint_as_float(u01.y << 16)          \
                + w10 * __uint_as_float(u10.y << 16) + w11 * __uint_as_float(u11.y << 16);         \
        ACC[3] += w00 * __uint_as_float(u00.y & 0xFFFF0000u) + w01 * __uint_as_float(u01.y & 0xFFFF0000u)  \
                + w10 * __uint_as_float(u10.y & 0xFFFF0000u) + w11 * __uint_as_float(u11.y & 0xFFFF0000u); \
        ACC[4] += w00 * __uint_as_float(u00.z << 16) + w01 * __uint_as_float(u01.z << 16)          \
                + w10 * __uint_as_float(u10.z << 16) + w11 * __uint_as_float(u11.z << 16);         \
        ACC[5] += w00 * __uint_as_float(u00.z & 0xFFFF0000u) + w01 * __uint_as_float(u01.z & 0xFFFF0000u)  \
                + w10 * __uint_as_float(u10.z & 0xFFFF0000u) + w11 * __uint_as_float(u11.z & 0xFFFF0000u); \
        ACC[6] += w00 * __uint_as_float(u00.w << 16) + w01 * __uint_as_float(u01.w << 16)          \
                + w10 * __uint_as_float(u10.w << 16) + w11 * __uint_as_float(u11.w << 16);         \
        ACC[7] += w00 * __uint_as_float(u00.w & 0xFFFF0000u) + w01 * __uint_as_float(u01.w & 0xFFFF0000u)  \
                + w10 * __uint_as_float(u10.w & 0xFFFF0000u) + w11 * __uint_as_float(u11.w & 0xFFFF0000u); \
    }

#pragma unroll
    for (int s = 0; s < SC; ++s) {
        float m0 = mk[0][s], m1 = mk[1][s];
        if (m0 == 0.f && m1 == 0.f) continue;    // uniform per block
        int base_s = (s * NH + h) * MV;
        SAMPLE_Q(acc0, rf[0][s][d][0], rf[0][s][d][1], qox0, qoy0, aw0, m0)
        SAMPLE_Q(acc1, rf[1][s][d][0], rf[1][s][d][1], qox1, qoy1, aw1, m1)
    }
#undef SAMPLE_Q

    *(float4*)&red[0][sid][coff]     = make_float4(acc0[0], acc0[1], acc0[2], acc0[3]);
    *(float4*)&red[0][sid][coff + 4] = make_float4(acc0[4], acc0[5], acc0[6], acc0[7]);
    *(float4*)&red[1][sid][coff]     = make_float4(acc1[0], acc1[1], acc1[2], acc1[3]);
    *(float4*)&red[1][sid][coff + 4] = make_float4(acc1[4], acc1[5], acc1[6], acc1[7]);
    __syncthreads();

    if (t < 256) {
        int qq = t >> 7, c = t & 127;
        int hh = c >> 5, ch = c & 31;
        float sum = 0.f;
#pragma unroll
        for (int p2 = 0; p2 < NP; ++p2) sum += red[qq][p2 * 4 + hh][ch];
        float cnt = mk[qq][0] + mk[qq][1] + mk[qq][2] + mk[qq][3] + mk[qq][4] + mk[qq][5];
        sl[qq][c] = sum / fmaxf(cnt, 1.0f);
    }
    __syncthreads();

    // ---- fused output projection + residual (both queries) ----
    if (t < 256) {
        int qq = t >> 7, c = t & 127;
        float acc = 0.f;
        for (int k = 0; k < CH; ++k) acc += sl[qq][k] * Wout[k * CH + c];
        int gi = (n0 + qq) * CH + c;
        out[gi] = acc + bout[c] + query[gi];
    }
}

extern "C" void kernel_launch(void* const* d_in, const int* in_sizes, int n_in,
                              void* d_out, int out_size, void* d_ws, size_t ws_size,
                              hipStream_t stream) {
    const float* query     = (const float*)d_in[0];
    const float* value     = (const float*)d_in[2];
    const float* query_pos = (const float*)d_in[3];
    const float* refcam    = (const float*)d_in[4];
    const void*  bev_mask  = (const void*)d_in[5];
    const float* Wv    = (const float*)d_in[8];
    const float* bv    = (const float*)d_in[9];
    const float* Woff  = (const float*)d_in[10];
    const float* boff  = (const float*)d_in[11];
    const float* Wattn = (const float*)d_in[12];
    const float* battn = (const float*)d_in[13];
    const float* Wout  = (const float*)d_in[14];
    const float* bout  = (const float*)d_in[15];

    float* wsf   = (float*)d_ws;
    int*   flag  = (int*)d_ws;
    float* qoff  = wsf + WS_QOFF;
    float* aw    = wsf + WS_AW;
    unsigned short* valw = (unsigned short*)(wsf + WS_VAL);
    float* out   = (float*)d_out;

    k_mega<<<NB_MEGA, 256, 0, stream>>>((const unsigned int*)bev_mask,
                                        query, query_pos, Woff, boff, Wattn, battn,
                                        value, Wv, bv, flag, qoff, aw, valw);
    k_sample3<<<NQ / 2, 320, 0, stream>>>(refcam, qoff, aw, bev_mask, flag, valw,
                                          Wout, bout, query, out);
}